// Round 3
// baseline (144.009 us; speedup 1.0000x reference)
//
#include <hip/hip_runtime.h>
#include <math.h>

// B=64, T=512, C=384, H=64. fp32 in/out; bf16 MFMA internally.
#define NB 64
#define NT 512
#define NC 384
#define NH 64

typedef __attribute__((ext_vector_type(8))) short bf16x8;
typedef __attribute__((ext_vector_type(4))) float f32x4;

__device__ __forceinline__ unsigned short f2bf(float f) {
  unsigned int u = __float_as_uint(f);
  return (unsigned short)((u + 0x7FFFu + ((u >> 16) & 1u)) >> 16);
}
__device__ __forceinline__ unsigned int pk2bf(float a, float b) {
  return (unsigned int)f2bf(a) | ((unsigned int)f2bf(b) << 16);
}

// ---------------------------------------------------------------------------
// Kernel 0: W[384][64] fp32 x3 -> Wt[192][384] bf16 (transposed, row-major)
// ---------------------------------------------------------------------------
__global__ __launch_bounds__(256) void wtrans_kernel(
    const float* __restrict__ Wq, const float* __restrict__ Wk,
    const float* __restrict__ Wv, unsigned short* __restrict__ Wt) {
  int id = blockIdx.x * 256 + threadIdx.x;
  if (id >= 3 * NC * NH) return;
  int m = id / (NC * NH);
  int r = id % (NC * NH);
  int c = r / NH;
  int h = r % NH;
  const float* W = (m == 0) ? Wq : ((m == 1) ? Wk : Wv);
  Wt[(m * NH + h) * NC + c] = f2bf(W[c * NH + h]);
}

// ---------------------------------------------------------------------------
// Kernel 1: fused QKV projection. M=32768, K=384, N=192.
// x tile (64 rows) staged bf16 in LDS once (1 barrier total); Wt B-frags
// read directly from global (147 KB, L2-hot). q scaled by 0.125 (exact).
// v written TRANSPOSED: Vt[b][h][t].
// ---------------------------------------------------------------------------
#define XS 392
__global__ __launch_bounds__(256) void proj_kernel(
    const float* __restrict__ x, const unsigned short* __restrict__ Wt,
    unsigned short* __restrict__ q, unsigned short* __restrict__ k,
    unsigned short* __restrict__ vt) {
  __shared__ unsigned short xs[64 * XS];
  const int t = threadIdx.x;
  const int m0 = blockIdx.x * 64;
  const int w = t >> 6, l = t & 63, mi = l & 15, quad = l >> 4;

  for (int i = 0; i < 24; ++i) {
    int u = t + i * 256;
    int row = u / 96;
    int cp = (u % 96) * 4;
    float4 a = *(const float4*)(x + (size_t)(m0 + row) * NC + cp);
    ushort4 bb;
    bb.x = f2bf(a.x); bb.y = f2bf(a.y); bb.z = f2bf(a.z); bb.w = f2bf(a.w);
    *(ushort4*)&xs[row * XS + cp] = bb;
  }
  __syncthreads();

  f32x4 acc[12];
  const f32x4 zero = {0.f, 0.f, 0.f, 0.f};
#pragma unroll
  for (int i = 0; i < 12; ++i) acc[i] = zero;

  for (int kc = 0; kc < 12; ++kc) {
    bf16x8 a = *(const bf16x8*)&xs[(w * 16 + mi) * XS + kc * 32 + quad * 8];
    const unsigned short* wp = Wt + (size_t)mi * NC + kc * 32 + quad * 8;
#pragma unroll
    for (int nt = 0; nt < 12; ++nt) {
      bf16x8 b = *(const bf16x8*)(wp + (size_t)nt * 16 * NC);
      acc[nt] = __builtin_amdgcn_mfma_f32_16x16x32_bf16(a, b, acc[nt], 0, 0, 0);
    }
  }

  // epilogue: C/D layout col=lane&15 (=n), row=quad*4+r (=m)
#pragma unroll
  for (int nt = 0; nt < 12; ++nt) {
    int n = nt * 16 + mi;
    int mat = n >> 6;
    int h = n & 63;
    if (mat < 2) {
      unsigned short* dst = (mat == 0) ? q : k;
      float sc = (mat == 0) ? 0.125f : 1.0f;  // fold 1/sqrt(64) into q (exact)
#pragma unroll
      for (int r = 0; r < 4; ++r) {
        int row = m0 + w * 16 + quad * 4 + r;
        dst[(size_t)row * NH + h] = f2bf(acc[nt][r] * sc);
      }
    } else {
#pragma unroll
      for (int r = 0; r < 4; ++r) {
        int row = m0 + w * 16 + quad * 4 + r;
        int bb = row >> 9, tt = row & 511;
        vt[((size_t)bb * NH + h) * NT + tt] = f2bf(acc[nt][r]);
      }
    }
  }
}

// ---------------------------------------------------------------------------
// Kernel 2: causal flash attention. Block = 4 waves, one (b, 64-row q-tile).
// S^T = K*Q^T so P^T lands row-contiguous in key dim: vectorized wave-local
// LDS round-trip (no barrier). V^T staged coalesced from precomputed Vt.
// ---------------------------------------------------------------------------
#define AS 72
__global__ __launch_bounds__(256) void attn_kernel(
    const unsigned short* __restrict__ q, const unsigned short* __restrict__ k,
    const unsigned short* __restrict__ vt, float* __restrict__ out) {
  __shared__ unsigned short ks[64 * AS];
  __shared__ unsigned short vts[64 * AS];
  __shared__ unsigned short ps[64 * AS];

  const int t = threadIdx.x;
  const int bx = blockIdx.x;
  const int qt = 7 - (bx >> 6);   // heavy q-tiles first
  const int b = bx & 63;
  const int w = t >> 6, l = t & 63, mi = l & 15, quad = l >> 4;

  // Q B-frags straight from global (coalesced within quads)
  const size_t qbase = ((size_t)b * NT + qt * 64) * NH;
  const unsigned short* qrow = q + qbase + (size_t)(w * 16 + mi) * NH;
  bf16x8 qb0 = *(const bf16x8*)(qrow + quad * 8);
  bf16x8 qb1 = *(const bf16x8*)(qrow + 32 + quad * 8);

  f32x4 accO[4];
  const f32x4 zero = {0.f, 0.f, 0.f, 0.f};
#pragma unroll
  for (int i = 0; i < 4; ++i) accO[i] = zero;
  float mrow = -INFINITY, lrow = 0.f;  // per lane: q-row = w*16 + mi

  for (int kt = 0; kt <= qt; ++kt) {
    const size_t kbase = ((size_t)b * NT + kt * 64) * NH;
    const size_t vtbase = (size_t)b * NH * NT + kt * 64;
    __syncthreads();  // prior-tile reads done
#pragma unroll
    for (int i = 0; i < 2; ++i) {
      int u = t + i * 256;
      int row = u >> 3, seg = u & 7;
      *(uint4*)&ks[row * AS + seg * 8] =
          *(const uint4*)&k[kbase + row * 64 + seg * 8];
      *(uint4*)&vts[row * AS + seg * 8] =
          *(const uint4*)&vt[vtbase + (size_t)row * NT + seg * 8];
    }
    __syncthreads();

    // S^T tile: A = K rows (m=key), B = Q rows (n=qrow).
    // Lane (mi,quad) reg r holds S[q=w*16+mi][key=nt*16+quad*4+r].
    float p[4][4];
#pragma unroll
    for (int nt = 0; nt < 4; ++nt) {
      bf16x8 a0 = *(const bf16x8*)&ks[(nt * 16 + mi) * AS + quad * 8];
      bf16x8 a1 = *(const bf16x8*)&ks[(nt * 16 + mi) * AS + 32 + quad * 8];
      f32x4 z = zero;
      z = __builtin_amdgcn_mfma_f32_16x16x32_bf16(a0, qb0, z, 0, 0, 0);
      z = __builtin_amdgcn_mfma_f32_16x16x32_bf16(a1, qb1, z, 0, 0, 0);
#pragma unroll
      for (int r = 0; r < 4; ++r) p[nt][r] = z[r];
    }

    if (kt == qt) {  // causal mask on diagonal tile
#pragma unroll
      for (int nt = 0; nt < 4; ++nt)
#pragma unroll
        for (int r = 0; r < 4; ++r)
          if (nt * 16 + quad * 4 + r > w * 16 + mi) p[nt][r] = -INFINITY;
    }

    // online softmax for q = w*16+mi (keys spread across quads: 2 shuffles)
    float vmax = -INFINITY;
#pragma unroll
    for (int nt = 0; nt < 4; ++nt)
#pragma unroll
      for (int r = 0; r < 4; ++r) vmax = fmaxf(vmax, p[nt][r]);
    vmax = fmaxf(vmax, __shfl_xor(vmax, 16));
    vmax = fmaxf(vmax, __shfl_xor(vmax, 32));
    float mn = fmaxf(mrow, vmax);
    float alpha = __expf(mrow - mn);
    mrow = mn;

    float rsum = 0.f;
#pragma unroll
    for (int nt = 0; nt < 4; ++nt)
#pragma unroll
      for (int r = 0; r < 4; ++r) {
        p[nt][r] = __expf(p[nt][r] - mn);
        rsum += p[nt][r];
      }
    rsum += __shfl_xor(rsum, 16);
    rsum += __shfl_xor(rsum, 32);
    lrow = lrow * alpha + rsum;

    // P row-contiguous store (wave-local, no barrier): ps[q][key]
#pragma unroll
    for (int nt = 0; nt < 4; ++nt) {
      uint2 pk;
      pk.x = pk2bf(p[nt][0], p[nt][1]);
      pk.y = pk2bf(p[nt][2], p[nt][3]);
      *(uint2*)&ps[(w * 16 + mi) * AS + nt * 16 + quad * 4] = pk;
    }
    bf16x8 pa0 = *(const bf16x8*)&ps[(w * 16 + mi) * AS + quad * 8];
    bf16x8 pa1 = *(const bf16x8*)&ps[(w * 16 + mi) * AS + 32 + quad * 8];

    // rescale accO (rows are q=quad*4+r -> fetch alpha from lane quad*4+r)
    float av[4];
#pragma unroll
    for (int r = 0; r < 4; ++r) av[r] = __shfl(alpha, quad * 4 + r);
#pragma unroll
    for (int hi = 0; hi < 4; ++hi)
#pragma unroll
      for (int r = 0; r < 4; ++r) accO[hi][r] *= av[r];

    // O += P V  (A = P rows, B = V^T rows; D col=h, row=q)
#pragma unroll
    for (int hi = 0; hi < 4; ++hi) {
      bf16x8 vb0 = *(const bf16x8*)&vts[(hi * 16 + mi) * AS + quad * 8];
      bf16x8 vb1 = *(const bf16x8*)&vts[(hi * 16 + mi) * AS + 32 + quad * 8];
      accO[hi] = __builtin_amdgcn_mfma_f32_16x16x32_bf16(pa0, vb0, accO[hi], 0, 0, 0);
      accO[hi] = __builtin_amdgcn_mfma_f32_16x16x32_bf16(pa1, vb1, accO[hi], 0, 0, 0);
    }
  }

  // epilogue
  float inv = 1.f / lrow;
  const size_t obase = ((size_t)b * NT + qt * 64) * NH;
#pragma unroll
  for (int r = 0; r < 4; ++r) {
    float iv = __shfl(inv, quad * 4 + r);
#pragma unroll
    for (int hi = 0; hi < 4; ++hi) {
      out[obase + (size_t)(w * 16 + quad * 4 + r) * NH + hi * 16 + mi] =
          accO[hi][r] * iv;
    }
  }
}

extern "C" void kernel_launch(void* const* d_in, const int* in_sizes, int n_in,
                              void* d_out, int out_size, void* d_ws, size_t ws_size,
                              hipStream_t stream) {
  const float* x  = (const float*)d_in[0];
  const float* Wq = (const float*)d_in[1];
  const float* Wk = (const float*)d_in[2];
  const float* Wv = (const float*)d_in[3];

  unsigned short* Wt = (unsigned short*)d_ws;          // 192*384
  unsigned short* qb = Wt + 192 * 384;                 // 32768*64 each
  unsigned short* kb = qb + 32768 * 64;
  unsigned short* vtb = kb + 32768 * 64;               // Vt[b][h][t]
  float* out = (float*)d_out;

  wtrans_kernel<<<288, 256, 0, stream>>>(Wq, Wk, Wv, Wt);
  proj_kernel<<<512, 256, 0, stream>>>(x, Wt, qb, kb, vtb);
  attn_kernel<<<512, 256, 0, stream>>>(qb, kb, vtb, out);
}

// Round 4
// 127.962 us; speedup vs baseline: 1.1254x; 1.1254x over previous
//
#include <hip/hip_runtime.h>
#include <math.h>

// B=64, T=512, C=384, H=64. fp32 in/out; bf16 MFMA internally.
#define NB 64
#define NT 512
#define NC 384
#define NH 64

typedef __attribute__((ext_vector_type(8))) short bf16x8;
typedef __attribute__((ext_vector_type(4))) float f32x4;

__device__ __forceinline__ unsigned short f2bf(float f) {
  unsigned int u = __float_as_uint(f);
  return (unsigned short)((u + 0x7FFFu + ((u >> 16) & 1u)) >> 16);
}
__device__ __forceinline__ unsigned int pk2bf(float a, float b) {
  return (unsigned int)f2bf(a) | ((unsigned int)f2bf(b) << 16);
}
__device__ __forceinline__ bf16x8 pack8(float4 lo, float4 hi) {
  union { bf16x8 v; unsigned short s[8]; } u;
  u.s[0] = f2bf(lo.x); u.s[1] = f2bf(lo.y); u.s[2] = f2bf(lo.z); u.s[3] = f2bf(lo.w);
  u.s[4] = f2bf(hi.x); u.s[5] = f2bf(hi.y); u.s[6] = f2bf(hi.z); u.s[7] = f2bf(hi.w);
  return u.v;
}

// ---------------------------------------------------------------------------
// Kernel 0: W[384][64] fp32 x3 -> Wt[192][384] bf16 (transposed, row-major)
// ---------------------------------------------------------------------------
__global__ __launch_bounds__(256) void wtrans_kernel(
    const float* __restrict__ Wq, const float* __restrict__ Wk,
    const float* __restrict__ Wv, unsigned short* __restrict__ Wt) {
  int id = blockIdx.x * 256 + threadIdx.x;
  if (id >= 3 * NC * NH) return;
  int m = id / (NC * NH);
  int r = id % (NC * NH);
  int c = r / NH;
  int h = r % NH;
  const float* W = (m == 0) ? Wq : ((m == 1) ? Wk : Wv);
  Wt[(m * NH + h) * NC + c] = f2bf(W[c * NH + h]);
}

// ---------------------------------------------------------------------------
// Kernel 1: fused QKV projection. M=32768, K=384, N=192.
// Wt staged in LDS in 3 K-chunks of 128 (52 KB, 6 barriers total). A-frags
// straight from global x (fp32 -> bf16 cvt in regs). q scaled by 0.125.
// V epilogue transposed through LDS -> coalesced vt[b][h][t] stores.
// ---------------------------------------------------------------------------
#define WSTR 136  // 128 cols + 8 pad (272 B row stride, 16B-aligned)
__global__ __launch_bounds__(256) void proj_kernel(
    const float* __restrict__ x, const unsigned short* __restrict__ Wt,
    unsigned short* __restrict__ q, unsigned short* __restrict__ k,
    unsigned short* __restrict__ vt) {
  __shared__ unsigned short ws[192 * WSTR];  // 52224 B
  const int t = threadIdx.x;
  const int m0 = blockIdx.x * 64;
  const int w = t >> 6, l = t & 63, mi = l & 15, quad = l >> 4;

  f32x4 acc[12];
  const f32x4 zero = {0.f, 0.f, 0.f, 0.f};
#pragma unroll
  for (int i = 0; i < 12; ++i) acc[i] = zero;

  const float* xrow = x + (size_t)(m0 + w * 16 + mi) * NC;

  for (int ko = 0; ko < 3; ++ko) {
    if (ko) __syncthreads();  // previous chunk reads done
#pragma unroll
    for (int i = 0; i < 12; ++i) {
      int u = t + i * 256;          // 3072 uint4 units: 192 rows x 16 segs
      int row = u >> 4, seg = u & 15;
      *(uint4*)&ws[row * WSTR + seg * 8] =
          *(const uint4*)&Wt[row * NC + ko * 128 + seg * 8];
    }
    __syncthreads();
#pragma unroll
    for (int kci = 0; kci < 4; ++kci) {
      const float* xp = xrow + ko * 128 + kci * 32 + quad * 8;
      float4 lo = *(const float4*)xp;
      float4 hi = *(const float4*)(xp + 4);
      bf16x8 a = pack8(lo, hi);
#pragma unroll
      for (int nt = 0; nt < 12; ++nt) {
        bf16x8 bf = *(const bf16x8*)&ws[(nt * 16 + mi) * WSTR + kci * 32 + quad * 8];
        acc[nt] = __builtin_amdgcn_mfma_f32_16x16x32_bf16(a, bf, acc[nt], 0, 0, 0);
      }
    }
  }

  // epilogue. C/D layout: col=lane&15 (=n), row=quad*4+r (=m within wave band)
  const int rbase = m0 + w * 16 + quad * 4;
#pragma unroll
  for (int nt = 0; nt < 4; ++nt)  // q, fold 1/sqrt(64)=0.125 (exact in bf16)
#pragma unroll
    for (int r = 0; r < 4; ++r)
      q[(size_t)(rbase + r) * NH + nt * 16 + mi] = f2bf(acc[nt][r] * 0.125f);
#pragma unroll
  for (int nt = 4; nt < 8; ++nt)  // k
#pragma unroll
    for (int r = 0; r < 4; ++r)
      k[(size_t)(rbase + r) * NH + (nt - 4) * 16 + mi] = f2bf(acc[nt][r]);

  // v: transpose via LDS (reuse ws), then coalesced store to vt[b][h][t]
  __syncthreads();  // all ws B-frag reads complete
#pragma unroll
  for (int nt = 8; nt < 12; ++nt) {
    int h = (nt - 8) * 16 + mi;
#pragma unroll
    for (int r = 0; r < 4; ++r)
      ws[h * 72 + w * 16 + quad * 4 + r] = f2bf(acc[nt][r]);
  }
  __syncthreads();
  {
    int bb = m0 >> 9, t0 = m0 & 511;
#pragma unroll
    for (int i = 0; i < 2; ++i) {
      int u = t + i * 256;          // 512 uint4 units: 64 h x 8 segs
      int h = u >> 3, seg = u & 7;
      *(uint4*)&vt[((size_t)bb * NH + h) * NT + t0 + seg * 8] =
          *(const uint4*)&ws[h * 72 + seg * 8];
    }
  }
}

// ---------------------------------------------------------------------------
// Kernel 2: causal flash attention. ONE WAVE per (b, 16-row q-tile).
// All fragments gathered directly from L2/L3-hot global (16 independent
// loads in flight per k-tile); P round-trip via wave-local LDS (2.3 KB);
// zero barriers. Grid 2048 = 8 blocks/CU; heavy q-tiles dispatched first.
// ---------------------------------------------------------------------------
#define PSTR 72
__global__ __launch_bounds__(64) void attn_kernel(
    const unsigned short* __restrict__ q, const unsigned short* __restrict__ k,
    const unsigned short* __restrict__ vt, float* __restrict__ out) {
  __shared__ unsigned short ps[16 * PSTR];
  const int l = threadIdx.x;
  const int mi = l & 15, quad = l >> 4;
  const int bx = blockIdx.x;
  const int qi = 31 - (bx >> 6);  // heavy tiles first
  const int b = bx & 63;

  // Q B-frags (row n=mi of the 16-row q-tile), loaded once
  const unsigned short* qrow = q + ((size_t)b * NT + qi * 16 + mi) * NH;
  bf16x8 qb0 = *(const bf16x8*)(qrow + quad * 8);
  bf16x8 qb1 = *(const bf16x8*)(qrow + 32 + quad * 8);

  f32x4 accO[4];
  const f32x4 zero = {0.f, 0.f, 0.f, 0.f};
#pragma unroll
  for (int i = 0; i < 4; ++i) accO[i] = zero;
  float mrow = -INFINITY, lrow = 0.f;  // per-lane q-row = qi*16 + mi

  const int ktmax = (qi * 16 + 15) >> 6;
  for (int kt = 0; kt <= ktmax; ++kt) {
    // issue ALL global loads up-front (independent; V latency hides behind
    // S-MFMA + softmax)
    const unsigned short* kb = k + ((size_t)b * NT + kt * 64) * NH;
    const unsigned short* vb = vt + (size_t)b * NH * NT + kt * 64;
    bf16x8 ka0[4], ka1[4], va0[4], va1[4];
#pragma unroll
    for (int nt = 0; nt < 4; ++nt) {
      const unsigned short* kr = kb + (size_t)(nt * 16 + mi) * NH + quad * 8;
      ka0[nt] = *(const bf16x8*)kr;
      ka1[nt] = *(const bf16x8*)(kr + 32);
      const unsigned short* vr = vb + (size_t)(nt * 16 + mi) * NT + quad * 8;
      va0[nt] = *(const bf16x8*)vr;
      va1[nt] = *(const bf16x8*)(vr + 32);
    }

    // S^T tile: A = K rows (m=key), B = Q rows (n=q).
    // Lane (mi,quad) reg r holds S[q=mi][key = nt*16 + quad*4 + r].
    float p[4][4];
#pragma unroll
    for (int nt = 0; nt < 4; ++nt) {
      f32x4 z = zero;
      z = __builtin_amdgcn_mfma_f32_16x16x32_bf16(ka0[nt], qb0, z, 0, 0, 0);
      z = __builtin_amdgcn_mfma_f32_16x16x32_bf16(ka1[nt], qb1, z, 0, 0, 0);
#pragma unroll
      for (int r = 0; r < 4; ++r) p[nt][r] = z[r];
    }

    if (kt == ktmax) {  // causal mask on diagonal tile
#pragma unroll
      for (int nt = 0; nt < 4; ++nt)
#pragma unroll
        for (int r = 0; r < 4; ++r)
          if (kt * 64 + nt * 16 + quad * 4 + r > qi * 16 + mi)
            p[nt][r] = -INFINITY;
    }

    // online softmax for q=mi (keys spread across quads: 2 shuffles)
    float vmax = -INFINITY;
#pragma unroll
    for (int nt = 0; nt < 4; ++nt)
#pragma unroll
      for (int r = 0; r < 4; ++r) vmax = fmaxf(vmax, p[nt][r]);
    vmax = fmaxf(vmax, __shfl_xor(vmax, 16));
    vmax = fmaxf(vmax, __shfl_xor(vmax, 32));
    float mn = fmaxf(mrow, vmax);
    float alpha = __expf(mrow - mn);
    mrow = mn;

    float rsum = 0.f;
#pragma unroll
    for (int nt = 0; nt < 4; ++nt)
#pragma unroll
      for (int r = 0; r < 4; ++r) {
        p[nt][r] = __expf(p[nt][r] - mn);
        rsum += p[nt][r];
      }
    rsum += __shfl_xor(rsum, 16);
    rsum += __shfl_xor(rsum, 32);
    lrow = lrow * alpha + rsum;

    // P -> LDS (row-contiguous, wave-local, no barrier) -> A-frags
#pragma unroll
    for (int nt = 0; nt < 4; ++nt) {
      uint2 pk;
      pk.x = pk2bf(p[nt][0], p[nt][1]);
      pk.y = pk2bf(p[nt][2], p[nt][3]);
      *(uint2*)&ps[mi * PSTR + nt * 16 + quad * 4] = pk;
    }
    bf16x8 pa0 = *(const bf16x8*)&ps[mi * PSTR + quad * 8];
    bf16x8 pa1 = *(const bf16x8*)&ps[mi * PSTR + 32 + quad * 8];

    // rescale accO (rows q=quad*4+r -> alpha from lane quad*4+r)
    float av[4];
#pragma unroll
    for (int r = 0; r < 4; ++r) av[r] = __shfl(alpha, quad * 4 + r);
#pragma unroll
    for (int hi = 0; hi < 4; ++hi)
#pragma unroll
      for (int r = 0; r < 4; ++r) accO[hi][r] *= av[r];

    // O += P V  (A = P rows, B = V^T rows; D col=h, row=q)
#pragma unroll
    for (int hi = 0; hi < 4; ++hi) {
      accO[hi] = __builtin_amdgcn_mfma_f32_16x16x32_bf16(pa0, va0[hi], accO[hi], 0, 0, 0);
      accO[hi] = __builtin_amdgcn_mfma_f32_16x16x32_bf16(pa1, va1[hi], accO[hi], 0, 0, 0);
    }
  }

  // epilogue
  float inv = 1.f / lrow;
  const size_t obase = ((size_t)b * NT + qi * 16) * NH;
#pragma unroll
  for (int r = 0; r < 4; ++r) {
    float iv = __shfl(inv, quad * 4 + r);
#pragma unroll
    for (int hi = 0; hi < 4; ++hi)
      out[obase + (size_t)(quad * 4 + r) * NH + hi * 16 + mi] = accO[hi][r] * iv;
  }
}

extern "C" void kernel_launch(void* const* d_in, const int* in_sizes, int n_in,
                              void* d_out, int out_size, void* d_ws, size_t ws_size,
                              hipStream_t stream) {
  const float* x  = (const float*)d_in[0];
  const float* Wq = (const float*)d_in[1];
  const float* Wk = (const float*)d_in[2];
  const float* Wv = (const float*)d_in[3];

  unsigned short* Wt = (unsigned short*)d_ws;          // 192*384
  unsigned short* qb = Wt + 192 * 384;                 // 32768*64 each
  unsigned short* kb = qb + 32768 * 64;
  unsigned short* vtb = kb + 32768 * 64;               // Vt[b][h][t]
  float* out = (float*)d_out;

  wtrans_kernel<<<288, 256, 0, stream>>>(Wq, Wk, Wv, Wt);
  proj_kernel<<<512, 256, 0, stream>>>(x, Wt, qb, kb, vtb);
  attn_kernel<<<2048, 64, 0, stream>>>(qb, kb, vtb, out);
}